// Round 8
// baseline (111.215 us; speedup 1.0000x reference)
//
#include <hip/hip_runtime.h>

// ImplicitModelLoRA: X = relu(s*L*(R^T X) + B U^T) iterated; out = (C X + D U^T)^T
// Round-8: k_main self-contained per column: L packed f16 into XOR-swizzled LDS
// (read every iter at 2 lanes/bank = conflict-free), R f16 in 32 VGPRs, norms
// computed in-block, fused epilogue. k_prep = pure BUt tile GEMM, plain stores.
// NIT=5: ||A||inf <= ||L||inf*||Rt||inf ~ 0.05*0.84 -> truncation ~ 6e-6 rel.

#define NIT 5

typedef _Float16 half2_t __attribute__((ext_vector_type(2)));

#define WS_BUT 0                       // 262144 f32: (B@U^T)^T [m][n]

__device__ __forceinline__ unsigned pk2h(float x, float y) {
  half2_t h;
  h.x = (_Float16)x;
  h.y = (_Float16)y;
  return __builtin_bit_cast(unsigned, h);
}

__device__ __forceinline__ unsigned short f2h(float x) {
  _Float16 h = (_Float16)x;
  return __builtin_bit_cast(unsigned short, h);
}

__device__ __forceinline__ float dot2(unsigned a, unsigned b, float acc) {
#if __has_builtin(__builtin_amdgcn_fdot2)
  return __builtin_amdgcn_fdot2(__builtin_bit_cast(half2_t, a),
                                __builtin_bit_cast(half2_t, b), acc, false);
#else
  half2_t ha = __builtin_bit_cast(half2_t, a);
  half2_t hb = __builtin_bit_cast(half2_t, b);
  acc = fmaf((float)ha.x, (float)hb.x, acc);
  acc = fmaf((float)ha.y, (float)hb.y, acc);
  return acc;
#endif
}

__device__ __forceinline__ float abssum2(unsigned u) {
  half2_t h = __builtin_bit_cast(half2_t, u & 0x7FFF7FFFu);
  return (float)h.x + (float)h.y;
}

// ---- K1: BUt[m][n] = sum_p B[n][p] U[m][p]. 32x32 tiles, K=512, swizzled
// LDS staging, plain stores. Grid (32,8) = 256 blocks.
__global__ __launch_bounds__(256) void k_prep(const float* __restrict__ B,
                                              const float* __restrict__ U,
                                              float* __restrict__ ws) {
  __shared__ __align__(16) float Us[32 * 32], Bs[32 * 32];
  int t = threadIdx.x;
  int n0 = blockIdx.x * 32, m0 = blockIdx.y * 32;
  int ti = t & 15, tj = t >> 4;
  int lr = t >> 3, lc = t & 7;
  float4* Us4 = (float4*)Us;
  float4* Bs4 = (float4*)Bs;
  const float4* U4 = (const float4*)U;
  const float4* B4 = (const float4*)B;
  float acc00 = 0, acc01 = 0, acc10 = 0, acc11 = 0;
  for (int kc = 0; kc < 16; ++kc) {
    __syncthreads();
    Us4[lr * 8 + (lc ^ (lr & 7))] = U4[(m0 + lr) * 128 + kc * 8 + lc];
    Bs4[lr * 8 + (lc ^ (lr & 7))] = B4[(n0 + lr) * 128 + kc * 8 + lc];
    __syncthreads();
#pragma unroll
    for (int k4 = 0; k4 < 8; ++k4) {
      float4 u0 = Us4[tj * 8 + (k4 ^ (tj & 7))];
      float4 u1 = Us4[(tj + 16) * 8 + (k4 ^ (tj & 7))];
      float4 b0 = Bs4[ti * 8 + (k4 ^ (ti & 7))];
      float4 b1 = Bs4[(ti + 16) * 8 + (k4 ^ (ti & 7))];
      acc00 += u0.x * b0.x + u0.y * b0.y + u0.z * b0.z + u0.w * b0.w;
      acc01 += u0.x * b1.x + u0.y * b1.y + u0.z * b1.z + u0.w * b1.w;
      acc10 += u1.x * b0.x + u1.y * b0.y + u1.z * b0.z + u1.w * b0.w;
      acc11 += u1.x * b1.x + u1.y * b1.y + u1.z * b1.z + u1.w * b1.w;
    }
  }
  float* BUt = ws + WS_BUT;
  BUt[(m0 + tj) * 1024 + n0 + ti] = acc00;
  BUt[(m0 + tj) * 1024 + n0 + ti + 16] = acc01;
  BUt[(m0 + tj + 16) * 1024 + n0 + ti] = acc10;
  BUt[(m0 + tj + 16) * 1024 + n0 + ti + 16] = acc11;
}

// ---- K2: everything else. 256 blocks x 1024 thr, 1 column of X each. -----
// L f16 in swizzled LDS (128 KB); R f16 in regs (32 VGPR); norms in-block;
// 4 loop iterations; fused epilogue out[c][q] = C[q,:].x + D[q,:].U[c,:].
__global__ __launch_bounds__(1024, 4) void k_main(const float* __restrict__ L,
                                                  const float* __restrict__ R,
                                                  const float* __restrict__ C,
                                                  const float* __restrict__ D,
                                                  const float* __restrict__ U,
                                                  float* __restrict__ ws,
                                                  float* __restrict__ out) {
  __shared__ __align__(16) uint2 L_lds[16384];     // 128 KB: row n = 16 uint2
  __shared__ __align__(16) unsigned short x_h[1024];
  __shared__ __align__(16) float xs32[1024];
  __shared__ __align__(16) float Us_s[512];
  __shared__ __align__(16) float tpart[16][64];
  __shared__ __align__(16) unsigned t_u[32];
  __shared__ float redL[16];
  __shared__ float s_sh;
  int tid = threadIdx.x, w = tid >> 6, lane = tid & 63;
  int c = blockIdx.x;
  // pack L -> LDS f16, swizzle: uint2 slot = n*16 + (k4 ^ ((n&7)<<1))
  const float4* L4 = (const float4*)L;
#pragma unroll
  for (int h = 0; h < 16; ++h) {
    int idx = h * 1024 + tid;                      // coalesced f32x4 reads
    float4 v = L4[idx];
    int n = idx >> 4, k4 = idx & 15;
    uint2 o;
    o.x = pk2h(v.x, v.y);
    o.y = pk2h(v.z, v.w);
    L_lds[n * 16 + (k4 ^ ((n & 7) << 1))] = o;
  }
  // R column `lane`, rows [w*64, w*64+64) -> f16 pairs in regs; colsum partial
  unsigned Rr[32];
  float cs = 0.f;
  int rbase = w * 64;
#pragma unroll
  for (int r2 = 0; r2 < 32; ++r2) {
    float lo = R[(rbase + 2 * r2) * 64 + lane];
    float hi = R[(rbase + 2 * r2 + 1) * 64 + lane];
    Rr[r2] = pk2h(lo, hi);
    cs += fabsf(lo) + fabsf(hi);
  }
  tpart[w][lane] = cs;
  float bu = ws[WS_BUT + c * 1024 + tid];
  __syncthreads();                                 // L_lds + tpart ready
  // ||L||inf from LDS row tid (f16 abs-sum; s=1 unless norms near 0.97)
  const uint4* Ld4 = (const uint4*)L_lds;
  {
    float rs = 0.f;
#pragma unroll
    for (int j = 0; j < 8; ++j) {
      uint4 lv = Ld4[tid * 8 + (j ^ (tid & 7))];
      rs += abssum2(lv.x) + abssum2(lv.y) + abssum2(lv.z) + abssum2(lv.w);
    }
#pragma unroll
    for (int m = 32; m; m >>= 1) rs = fmaxf(rs, __shfl_xor(rs, m));
    if (lane == 0) redL[w] = rs;
  }
  float a = fmaxf(bu, 0.f);                        // X1 = relu(BU)
  x_h[tid] = f2h(a);
  __syncthreads();                                 // redL + x_h ready
  if (tid < 64) {
    float col = 0.f;
#pragma unroll
    for (int g = 0; g < 16; ++g) col += tpart[g][tid];
#pragma unroll
    for (int m = 32; m; m >>= 1) col = fmaxf(col, __shfl_xor(col, m));
    if (tid == 0) {
      float nL = 0.f;
#pragma unroll
      for (int g = 0; g < 16; ++g) nL = fmaxf(nL, redL[g]);
      s_sh = (nL > 0.97f ? 0.97f / nL : 1.f) * (col > 0.97f ? 0.97f / col : 1.f);
    }
  }
  __syncthreads();                                 // s_sh ready
  float s = s_sh;
  const uint4* xh4 = (const uint4*)x_h;
  const uint4* t4 = (const uint4*)t_u;
  for (int it = 0; it < NIT - 1; ++it) {
    // phase 2: tpart[w][lane] = sum_{n in wave rows} R[n][lane]*x[n] (wave-local)
    float t0 = 0.f, t1 = 0.f, t2 = 0.f, t3 = 0.f;
#pragma unroll
    for (int r = 0; r < 8; ++r) {
      uint4 xv = xh4[w * 8 + r];                   // broadcast read
      t0 = dot2(Rr[4 * r + 0], xv.x, t0);
      t1 = dot2(Rr[4 * r + 1], xv.y, t1);
      t2 = dot2(Rr[4 * r + 2], xv.z, t2);
      t3 = dot2(Rr[4 * r + 3], xv.w, t3);
    }
    tpart[w][lane] = (t0 + t1) + (t2 + t3);
    __syncthreads();
    if (tid < 32) {                                // t = s*(R^T x) as f16 pairs
      float sa = 0.f, sb = 0.f;
#pragma unroll
      for (int g = 0; g < 16; ++g) {
        sa += tpart[g][2 * tid];
        sb += tpart[g][2 * tid + 1];
      }
      t_u[tid] = pk2h(s * sa, s * sb);
    }
    __syncthreads();
    // phase 1: x[tid] = relu(bu + L[tid,:].t) -- L from swizzled LDS (2/bank)
    float b0 = 0.f, b1 = 0.f, b2 = 0.f, b3 = 0.f;
#pragma unroll
    for (int j = 0; j < 8; ++j) {
      uint4 lv = Ld4[tid * 8 + (j ^ (tid & 7))];
      uint4 tv = t4[j];
      b0 = dot2(lv.x, tv.x, b0);
      b1 = dot2(lv.y, tv.y, b1);
      b2 = dot2(lv.z, tv.z, b2);
      b3 = dot2(lv.w, tv.w, b3);
    }
    a = fmaxf(bu + ((b0 + b1) + (b2 + b3)), 0.f);
    x_h[tid] = f2h(a);                             // wave-local: no barrier
  }
  // ---- fused epilogue: out[c][q] = C[q,:].x + D[q,:].U[c,:] ----
  xs32[tid] = a;
  if (tid < 512) Us_s[tid] = U[c * 512 + tid];
  __syncthreads();
  const float4* C4 = (const float4*)C;
  const float4* D4 = (const float4*)D;
  const float4* xs4 = (const float4*)xs32;
  const float4* Us4 = (const float4*)Us_s;
#pragma unroll 1
  for (int i = 0; i < 16; ++i) {
    int q = w * 16 + i;
    float acc = 0.f;
#pragma unroll
    for (int seg = 0; seg < 4; ++seg) {
      float4 cv = C4[q * 256 + seg * 64 + lane];
      float4 xv = xs4[seg * 64 + lane];
      acc += cv.x * xv.x + cv.y * xv.y + cv.z * xv.z + cv.w * xv.w;
    }
#pragma unroll
    for (int seg = 0; seg < 2; ++seg) {
      float4 dv = D4[q * 128 + seg * 64 + lane];
      float4 uv = Us4[seg * 64 + lane];
      acc += dv.x * uv.x + dv.y * uv.y + dv.z * uv.z + dv.w * uv.w;
    }
#pragma unroll
    for (int m = 32; m; m >>= 1) acc += __shfl_xor(acc, m);
    if (lane == 0) out[c * 256 + q] = acc;
  }
}

extern "C" void kernel_launch(void* const* d_in, const int* in_sizes, int n_in,
                              void* d_out, int out_size, void* d_ws, size_t ws_size,
                              hipStream_t stream) {
  const float* U = (const float*)d_in[0];
  const float* L = (const float*)d_in[1];
  const float* R = (const float*)d_in[2];
  const float* B = (const float*)d_in[3];
  const float* C = (const float*)d_in[4];
  const float* D = (const float*)d_in[5];
  float* ws = (float*)d_ws;
  float* out = (float*)d_out;
  hipLaunchKernelGGL(k_prep, dim3(32, 8), dim3(256), 0, stream, B, U, ws);
  hipLaunchKernelGGL(k_main, dim3(256), dim3(1024), 0, stream, L, R, C, D, U, ws, out);
}